// Round 14
// baseline (515.556 us; speedup 1.0000x reference)
//
#include <hip/hip_runtime.h>

#define N_PTS 131072
#define KC    512
#define DIM   64
#define MAXIT 5
#define NCHUNK 64
#define CHUNK_PTS (N_PTS / NCHUNK)    // 2048
#define FIXSCALE 1099511627776.0      // 2^40

typedef short v8s __attribute__((ext_vector_type(8)));
typedef float v4f __attribute__((ext_vector_type(4)));

// f32 -> bf16 bits, RTNE (normals; inputs are O(1) gaussians + residuals)
__device__ __forceinline__ unsigned short bf16_rtne(float x) {
    unsigned int u = __float_as_uint(x);
    return (unsigned short)((u + 0x7FFFu + ((u >> 16) & 1u)) >> 16);
}
__device__ __forceinline__ float bf16_f32(unsigned short b) {
    return __uint_as_float(((unsigned int)b) << 16);
}
// 3-way split: x == h + m + l exactly (24 mantissa bits captured)
__device__ __forceinline__ void split3(float x, short& h, short& m, short& l) {
    unsigned short hb = bf16_rtne(x);
    float r1 = x - bf16_f32(hb);
    unsigned short mb = bf16_rtne(r1);
    float r2 = r1 - bf16_f32(mb);
    h = (short)hb; m = (short)mb; l = (short)bf16_rtne(r2);
}

// ---------------------------------------------------------------------------
// prep (once per launch): c2[k] (round-2 tree, bit-identical) + 3-way bf16
// split of C0 + zero qsums/counts (replaces the per-iter memset dispatches;
// d_ws is re-poisoned 0xAA before every launch, so prep must zero each time).
// ---------------------------------------------------------------------------
__global__ __launch_bounds__(256) void prep_kernel(
        const float* __restrict__ C, float* __restrict__ c2out,
        unsigned short* __restrict__ Ch, unsigned short* __restrict__ Cm,
        unsigned short* __restrict__ Cl,
        unsigned long long* __restrict__ qsums, int* __restrict__ counts) {
    int k = blockIdx.x * 256 + threadIdx.x;
    if (k < KC) {
        float sq[DIM];
        #pragma unroll
        for (int j = 0; j < DIM; ++j) {
            float c = C[k * DIM + j];
            sq[j] = c * c;
            short h, m, l;
            split3(c, h, m, l);
            Ch[k * DIM + j] = (unsigned short)h;
            Cm[k * DIM + j] = (unsigned short)m;
            Cl[k * DIM + j] = (unsigned short)l;
        }
        #pragma unroll
        for (int st = 1; st < DIM; st <<= 1)
            #pragma unroll
            for (int j = 0; j < DIM; j += 2 * st)
                sq[j] = sq[j] + sq[j + st];
        c2out[k] = sq[0];
    }
    int t = blockIdx.x * 256 + threadIdx.x;   // 512 threads total
    for (int i = t; i < KC * DIM; i += 512) qsums[i] = 0ull;
    if (t < KC) counts[t] = 0;
}

// ---------------------------------------------------------------------------
// assign kernel, ROUND 14: r13's LDS-staged bf16-split MFMA with 64-center
// staging (24 KB) per barrier pair: 8 stages x 4 subtiles of 16 centers.
// Barriers 64 -> 16; 96 MFMA per stage per wave (was 24) amortizes the
// stage/drain convoy; prefetch in-flight window ~4 GEMMs. The per-subtile
// MFMA order, d2 epilogue, and argmin are VERBATIM r13 (global subtile
// g = s*4+sub ascending = r13's ct) -> bit-identical assignments.
// Staging chunk c in [0,1536): sub=c/384, seg=(c%384)>>6 (split sp=seg>>1,
// kc=seg&1), lane l2=c&63 (center=l2&15, q2=l2>>4); wave-uniform sub/seg.
// ---------------------------------------------------------------------------
__global__ __launch_bounds__(256, 3) void assign_kernel(
        const float* __restrict__ X,
        const unsigned short* __restrict__ Ch,
        const unsigned short* __restrict__ Cm,
        const unsigned short* __restrict__ Cl,
        const float* __restrict__ c2v, float* __restrict__ out_f) {
    __shared__ short Bt[1536 * 8];       // 24 KB: [4 sub][6 seg][64 lanes] v8s
    __shared__ float c2t[KC];            // 2 KB
    __shared__ float x2p[4][2][16][8];   // 4 KB
    __shared__ float x2f[4][2][16];      // 0.5 KB

    const int t   = threadIdx.x;
    const int wv  = t >> 6;
    const int l   = t & 63;
    const int row = l & 15;       // A: point-in-tile; B: center-in-tile (D col)
    const int q   = l >> 4;       // k-quad; D rows = q*4+r
    const int pbase = blockIdx.x * 128 + wv * 32;

    for (int i = t; i < KC; i += 256) c2t[i] = c2v[i];

    // ---- A fragments (3 splits x 2 k-chunks x 2 point-tiles) + x2 partials
    v8s ah[2][2], am[2][2], al[2][2];
    #pragma unroll
    for (int T = 0; T < 2; ++T) {
        const float* xr = X + (size_t)(pbase + T * 16 + row) * DIM + q * 8;
        #pragma unroll
        for (int kc = 0; kc < 2; ++kc) {
            float4 v0 = *(const float4*)(xr + kc * 32);
            float4 v1 = *(const float4*)(xr + kc * 32 + 4);
            float e[8] = { v0.x, v0.y, v0.z, v0.w, v1.x, v1.y, v1.z, v1.w };
            v8s H, M, L;
            #pragma unroll
            for (int j = 0; j < 8; ++j) {
                short hh, mm, ll;
                split3(e[j], hh, mm, ll);
                H[j] = hh; M[j] = mm; L[j] = ll;
            }
            ah[T][kc] = H; am[T][kc] = M; al[T][kc] = L;
            float s0 = e[0]*e[0], s1 = e[1]*e[1], s2 = e[2]*e[2], s3 = e[3]*e[3];
            float s4 = e[4]*e[4], s5 = e[5]*e[5], s6 = e[6]*e[6], s7 = e[7]*e[7];
            x2p[wv][T][row][kc * 4 + q] =
                ((s0 + s1) + (s2 + s3)) + ((s4 + s5) + (s6 + s7));
        }
    }
    __syncthreads();
    if (t < 128) {
        int w2 = t >> 5, T2 = (t >> 4) & 1, pt = t & 15;
        const float* P = x2p[w2][T2][pt];
        x2f[w2][T2][pt] = ((P[0] + P[1]) + (P[2] + P[3]))
                        + ((P[4] + P[5]) + (P[6] + P[7]));
    }
    __syncthreads();
    float x2x[2][4];
    #pragma unroll
    for (int T = 0; T < 2; ++T)
        #pragma unroll
        for (int r = 0; r < 4; ++r)
            x2x[T][r] = x2f[wv][T][q * 4 + r];

    float bd[2][4];
    int   bk[2][4];
    #pragma unroll
    for (int T = 0; T < 2; ++T)
        #pragma unroll
        for (int r = 0; r < 4; ++r) { bd[T][r] = 3.4e38f; bk[T][r] = 0; }

    const unsigned short* const bases[3] = { Ch, Cm, Cl };
    #define CHUNK_GPTR(c, s) ((const v8s*)(bases[((c) % 384) >> 7] +          \
        ((size_t)((s) * 64 + ((c) / 384) * 16 + ((c) & 15)) * 64 +            \
         ((((c) % 384) >> 6) & 1) * 32 + (((c) & 63) >> 4) * 8)))

    // prologue: prefetch stage 0 into registers (6 v8s per thread)
    v8s rr[6];
    #pragma unroll
    for (int r = 0; r < 6; ++r) rr[r] = *CHUNK_GPTR(t + 256 * r, 0);

    v8s* const BtV = (v8s*)Bt;
    for (int s = 0; s < 8; ++s) {
        __syncthreads();                 // all waves done reading Bt (prev)
        #pragma unroll
        for (int r = 0; r < 6; ++r) BtV[t + 256 * r] = rr[r];
        if (s < 7) {                     // prefetch s+1 (in flight over 4 GEMMs)
            #pragma unroll
            for (int r = 0; r < 6; ++r) rr[r] = *CHUNK_GPTR(t + 256 * r, s + 1);
        }
        __syncthreads();                 // Bt ready

        #pragma unroll
        for (int sub = 0; sub < 4; ++sub) {
            v8s bh0 = BtV[sub * 384 + 0 * 64 + l];
            v8s bh1 = BtV[sub * 384 + 1 * 64 + l];
            v8s bm0 = BtV[sub * 384 + 2 * 64 + l];
            v8s bm1 = BtV[sub * 384 + 3 * 64 + l];
            v8s bl0 = BtV[sub * 384 + 4 * 64 + l];
            v8s bl1 = BtV[sub * 384 + 5 * 64 + l];
            float c2k = c2t[s * 64 + sub * 16 + row];
            int   kk  = s * 64 + sub * 16 + row;

            #pragma unroll
            for (int T = 0; T < 2; ++T) {
                v4f acc = {0.f, 0.f, 0.f, 0.f};
                acc = __builtin_amdgcn_mfma_f32_16x16x32_bf16(ah[T][0], bh0, acc, 0, 0, 0);
                acc = __builtin_amdgcn_mfma_f32_16x16x32_bf16(ah[T][1], bh1, acc, 0, 0, 0);
                acc = __builtin_amdgcn_mfma_f32_16x16x32_bf16(am[T][0], bh0, acc, 0, 0, 0);
                acc = __builtin_amdgcn_mfma_f32_16x16x32_bf16(am[T][1], bh1, acc, 0, 0, 0);
                acc = __builtin_amdgcn_mfma_f32_16x16x32_bf16(ah[T][0], bm0, acc, 0, 0, 0);
                acc = __builtin_amdgcn_mfma_f32_16x16x32_bf16(ah[T][1], bm1, acc, 0, 0, 0);
                acc = __builtin_amdgcn_mfma_f32_16x16x32_bf16(am[T][0], bm0, acc, 0, 0, 0);
                acc = __builtin_amdgcn_mfma_f32_16x16x32_bf16(am[T][1], bm1, acc, 0, 0, 0);
                acc = __builtin_amdgcn_mfma_f32_16x16x32_bf16(al[T][0], bh0, acc, 0, 0, 0);
                acc = __builtin_amdgcn_mfma_f32_16x16x32_bf16(al[T][1], bh1, acc, 0, 0, 0);
                acc = __builtin_amdgcn_mfma_f32_16x16x32_bf16(ah[T][0], bl0, acc, 0, 0, 0);
                acc = __builtin_amdgcn_mfma_f32_16x16x32_bf16(ah[T][1], bl1, acc, 0, 0, 0);
                #pragma unroll
                for (int r = 0; r < 4; ++r) {
                    float tt = x2x[T][r] + c2k;
                    float d2 = fmaf(-2.0f, acc[r], tt);
                    if (d2 < bd[T][r]) { bd[T][r] = d2; bk[T][r] = kk; }
                }
            }
        }
    }
    #undef CHUNK_GPTR

    // ---- cross-lane argmin over the 16 center residues (lane bits 0..3)
    #pragma unroll
    for (int T = 0; T < 2; ++T)
        #pragma unroll
        for (int r = 0; r < 4; ++r) {
            unsigned int b = __float_as_uint(bd[T][r]);
            b = (b & 0x80000000u) ? ~b : (b | 0x80000000u);
            unsigned long long key = ((unsigned long long)b << 32)
                                   | (unsigned int)bk[T][r];
            #pragma unroll
            for (int st = 1; st <= 8; st <<= 1) {
                unsigned long long o = __shfl_xor(key, st, 64);
                if (o < key) key = o;
            }
            if (row == 0) {
                int p = pbase + T * 16 + q * 4 + r;
                out_f[p] = (float)((int)(unsigned int)key);
            }
        }
}

// ---------------------------------------------------------------------------
// accumulate: 256 blocks x 1024 threads = 64 chunks x 4 dim-slices, 16
// waves/CU (was 4 — LDS-atomic latency now hidden). INT64 fixed-point LDS +
// global atomics: order-independent -> bit-deterministic (round-5 proven).
// ---------------------------------------------------------------------------
__global__ __launch_bounds__(1024) void accum_kernel(
        const float* __restrict__ X, const float* __restrict__ af,
        unsigned long long* __restrict__ qsums, int* __restrict__ counts) {
    __shared__ unsigned long long lsum[KC * 16];   // 64 KB
    __shared__ int lcnt[KC];
    int slice = blockIdx.x & 3;
    int chunk = blockIdx.x >> 2;
    int p4 = threadIdx.x >> 2;   // 0..255: point lane
    int c4 = threadIdx.x & 3;

    for (int i = threadIdx.x; i < KC * 16; i += 1024) lsum[i] = 0ull;
    if (threadIdx.x < KC) lcnt[threadIdx.x] = 0;
    __syncthreads();

    int base = chunk * CHUNK_PTS;
    #pragma unroll 2
    for (int it = 0; it < CHUNK_PTS / 256; ++it) {
        int n = base + it * 256 + p4;
        int a = (int)af[n];
        float4 xv = *(const float4*)(X + (size_t)n * DIM + slice * 16 + c4 * 4);
        long long q0 = (long long)llrint((double)xv.x * FIXSCALE);
        long long q1 = (long long)llrint((double)xv.y * FIXSCALE);
        long long q2 = (long long)llrint((double)xv.z * FIXSCALE);
        long long q3 = (long long)llrint((double)xv.w * FIXSCALE);
        atomicAdd(&lsum[a * 16 + c4 * 4 + 0], (unsigned long long)q0);
        atomicAdd(&lsum[a * 16 + c4 * 4 + 1], (unsigned long long)q1);
        atomicAdd(&lsum[a * 16 + c4 * 4 + 2], (unsigned long long)q2);
        atomicAdd(&lsum[a * 16 + c4 * 4 + 3], (unsigned long long)q3);
        if (slice == 0 && c4 == 0) atomicAdd(&lcnt[a], 1);
    }
    __syncthreads();

    for (int i = threadIdx.x; i < KC * 16; i += 1024) {
        unsigned long long v = lsum[i];
        if (v != 0ull)
            atomicAdd(&qsums[(i >> 4) * DIM + slice * 16 + (i & 15)], v);
    }
    if (slice == 0 && threadIdx.x < KC) {
        int v = lcnt[threadIdx.x];
        if (v != 0) atomicAdd(&counts[threadIdx.x], v);
    }
}

// ---------------------------------------------------------------------------
// update: centers = sums/max(cnt,1), ==0 -> re-seed; writes f32 centers to
// d_out tail, next iter's c2 (same butterfly tree) + 3-way bf16 splits.
// Also RE-ZEROES qsums/counts after the (single) read of each element —
// replaces the per-iter memset dispatch. Identical work every call.
// ---------------------------------------------------------------------------
__global__ __launch_bounds__(256) void update_kernel(
        unsigned long long* __restrict__ qsums,
        int* __restrict__ counts,
        const int* __restrict__ repl, const float* __restrict__ X,
        float* __restrict__ outC, float* __restrict__ c2v,
        unsigned short* __restrict__ Ch, unsigned short* __restrict__ Cm,
        unsigned short* __restrict__ Cl) {
    int k = blockIdx.x * 4 + (threadIdx.x >> 6);
    int d = threadIdx.x & 63;
    int idx = k * DIM + d;

    long long qq = (long long)qsums[idx];
    float cnt = (float)counts[k];
    qsums[idx] = 0ull;                    // re-zero for next iteration
    if (d == 0) counts[k] = 0;            // wave-lockstep: all reads done

    float s = (float)((double)qq * (1.0 / FIXSCALE));
    float v = s / fmaxf(cnt, 1.0f);
    if (v == 0.0f) v = X[(size_t)repl[k] * DIM + d];
    outC[idx] = v;

    short h, m, l;
    split3(v, h, m, l);
    Ch[idx] = (unsigned short)h;
    Cm[idx] = (unsigned short)m;
    Cl[idx] = (unsigned short)l;

    float sq = v * v;
    #pragma unroll
    for (int st = 1; st < 64; st <<= 1)
        sq += __shfl_xor(sq, st, 64);
    if (d == 0) c2v[k] = sq;
}

// ---------------------------------------------------------------------------
extern "C" void kernel_launch(void* const* d_in, const int* in_sizes, int n_in,
                              void* d_out, int out_size, void* d_ws, size_t ws_size,
                              hipStream_t stream) {
    const float* X    = (const float*)d_in[0];   // [N, D]
    const float* C0   = (const float*)d_in[1];   // [K, D]
    const int*   repl = (const int*)d_in[2];     // [MAXIT, K]
    float* out = (float*)d_out;                  // [N] assignments + [K*D] centers

    // ws: 452 KB total (round-2's 920 KB proved safe; round-3's 12.8 MB not).
    char* ws = (char*)d_ws;
    unsigned short* Ch = (unsigned short*)(ws + 0);            // 64 KB
    unsigned short* Cm = (unsigned short*)(ws + (64 << 10));   // 64 KB
    unsigned short* Cl = (unsigned short*)(ws + (128 << 10));  // 64 KB
    unsigned long long* qsums = (unsigned long long*)(ws + (192 << 10)); // 256 KB
    int*   counts = (int*)  (ws + (448 << 10));                // 2 KB
    float* c2v    = (float*)(ws + (450 << 10));                // 2 KB

    prep_kernel<<<2, 256, 0, stream>>>(C0, c2v, Ch, Cm, Cl, qsums, counts);

    for (int i = 0; i < MAXIT; ++i) {
        assign_kernel<<<N_PTS / 128, 256, 0, stream>>>(
            X, Ch, Cm, Cl, c2v, out);

        accum_kernel<<<NCHUNK * 4, 1024, 0, stream>>>(X, out, qsums, counts);

        update_kernel<<<KC / 4, 256, 0, stream>>>(
            qsums, counts, repl + i * KC, X, out + N_PTS, c2v, Ch, Cm, Cl);
    }
}